// Round 4
// baseline (277.182 us; speedup 1.0000x reference)
//
#include <hip/hip_runtime.h>
#include <hip/hip_bf16.h>
#include <stdint.h>

#define ALPHA 1.0f

typedef __attribute__((ext_vector_type(8))) short bf16x8;
typedef __attribute__((ext_vector_type(4))) float f32x4;

__device__ __forceinline__ unsigned short f32_to_bf16_rne(float f) {
    union { float f; unsigned int u; } v; v.f = f;
    unsigned int u = v.u;
    unsigned int r = u + 0x7FFFu + ((u >> 16) & 1u);
    return (unsigned short)(r >> 16);
}

// packed f32x2 -> bf16x2 (RNE), single VALU instruction; word = [lo | hi<<16]
__device__ __forceinline__ unsigned int cvt_pk_bf16(float lo, float hi) {
    unsigned int r;
    asm("v_cvt_pk_bf16_f32 %0, %1, %2" : "=v"(r) : "v"(lo), "v"(hi));
    return r;
}

__device__ __forceinline__ void async_copy16(const void* g, void* l) {
    __builtin_amdgcn_global_load_lds(
        (const __attribute__((address_space(1))) void*)g,
        (__attribute__((address_space(3))) void*)l, 16, 0, 0);
}

// ---------------------------------------------------------------------------
// Step 1a: t2[50][1024] = lora_up (50x4) @ (lora_down (4x100) @ down_aux (100x1024))
__global__ void lilora_t2_kernel(const float* __restrict__ lora_down,
                                 const float* __restrict__ lora_up,
                                 const float* __restrict__ down_aux,
                                 float* __restrict__ t2) {
    int i = threadIdx.x;  // 0..1023 column
    float t1[4] = {0.f, 0.f, 0.f, 0.f};
    for (int d = 0; d < 100; ++d) {
        float da = down_aux[d * 1024 + i];
#pragma unroll
        for (int r = 0; r < 4; ++r) t1[r] += lora_down[r * 100 + d] * da;
    }
    for (int u = 0; u < 50; ++u) {
        float acc = 0.f;
#pragma unroll
        for (int r = 0; r < 4; ++r) acc += lora_up[u * 4 + r] * t1[r];
        t2[u * 1024 + i] = acc;
    }
}

// ---------------------------------------------------------------------------
// Step 1b: W_eff[o][i] = W[o][i] + ALPHA * sum_u up_aux[o][u] * t2[u][i]  (bf16 out)
__global__ __launch_bounds__(256)
void weff_bf16_kernel(const float* __restrict__ W, const float* __restrict__ up_aux,
                      const float* __restrict__ t2, unsigned short* __restrict__ weff) {
    int o = blockIdx.x;
    int i0 = threadIdx.x * 4;
    float4 acc = *(const float4*)(W + (long)o * 1024 + i0);
    for (int u = 0; u < 50; ++u) {
        float s = up_aux[o * 50 + u] * ALPHA;
        float4 t = *(const float4*)(t2 + u * 1024 + i0);
        acc.x += s * t.x; acc.y += s * t.y; acc.z += s * t.z; acc.w += s * t.w;
    }
    ushort4 r;
    r.x = f32_to_bf16_rne(acc.x);
    r.y = f32_to_bf16_rne(acc.y);
    r.z = f32_to_bf16_rne(acc.z);
    r.w = f32_to_bf16_rne(acc.w);
    *(ushort4*)(weff + (long)o * 1024 + i0) = r;
}

// f32 variant for the fallback path
__global__ __launch_bounds__(256)
void weff_f32_kernel(const float* __restrict__ W, const float* __restrict__ up_aux,
                     const float* __restrict__ t2, float* __restrict__ weff) {
    int o = blockIdx.x;
    int i0 = threadIdx.x * 4;
    float4 acc = *(const float4*)(W + (long)o * 1024 + i0);
    for (int u = 0; u < 50; ++u) {
        float s = up_aux[o * 50 + u] * ALPHA;
        float4 t = *(const float4*)(t2 + u * 1024 + i0);
        acc.x += s * t.x; acc.y += s * t.y; acc.z += s * t.z; acc.w += s * t.w;
    }
    *(float4*)(weff + (long)o * 1024 + i0) = acc;
}

// ---------------------------------------------------------------------------
// Fused GEMM: C[M][N] = cvt_bf16(A_f32[M][K]) * Bt_bf16[N][K]^T + bias
// 128x128 tile, BK=64, 4 waves (2x2), wave = 64x64 out = 4x4 frags 16x16x32.
//
// SINGLE-BARRIER double-buffered pipeline:
//  - A: global f32 -> regs (coalesced 32B/lane) -> cvt_pk -> bf16 ds_write,
//    converted ONCE per element at stage time. The cvt of tile t+1 consumes
//    regs issued during iter t-1 (guaranteed arrived by barrier vmcnt drain).
//  - B: global_load_lds bf16 with pre-swizzled source (rule #21).
//  - Both LDS tiles [row][64 bf16 = 8 x 16B chunks], XOR-swizzled:
//    stored[pos] = logical[pos ^ (row&7)]  (R2-verified: 0 bank conflicts).
#define BM 128
#define BN 128
#define BK 64

__global__ __launch_bounds__(256, 2)
void gemm_fused_kernel(const float* __restrict__ A,
                       const unsigned short* __restrict__ Bt,
                       const float* __restrict__ bias,
                       float* __restrict__ C, int M, int N, int K) {
    __shared__ __align__(16) unsigned short As[2][BM * BK];  // 2 x 16 KB
    __shared__ __align__(16) unsigned short Bs[2][BN * BK];  // 2 x 16 KB

    int nTilesN = N / BN;
    int nwg = gridDim.x;
    int bid = blockIdx.x;
    // XCD-aware swizzle (bijective when nwg % 8 == 0; here grid = 4096)
    int swz = bid;
    if ((nwg & 7) == 0) {
        int cpx = nwg >> 3;
        swz = (bid & 7) * cpx + (bid >> 3);
    }
    int tm = swz / nTilesN;   // tn fastest -> 8 blocks sharing an A panel
    int tn = swz % nTilesN;   // run back-to-back on the same XCD (A L2-hot)

    int tid = threadIdx.x;
    int lane = tid & 63;
    int wave = tid >> 6;   // 0..3
    int wr = wave >> 1;    // 0..1
    int wc = wave & 1;     // 0..1

    const long rowA0 = (long)tm * BM;
    const long colB0 = (long)tn * BN;

    // ---- A staging map: pair p = q*256 + tid (q=0..3) covers 32B of f32 ----
    //   row ar = p>>3 (0..127), global chunk acg = p&7 (f32 col = acg*8),
    //   LDS chunk pos acl = acg ^ (ar&7)
    int ar_[4], acg_[4], acl_[4];
#pragma unroll
    for (int q = 0; q < 4; ++q) {
        int p = q * 256 + tid;
        ar_[q]  = p >> 3;
        acg_[q] = p & 7;
        acl_[q] = acg_[q] ^ (ar_[q] & 7);
    }

    // ---- B staging map (glds, pre-swizzled source) ----
    int brow[4], bchk[4];
#pragma unroll
    for (int q = 0; q < 4; ++q) {
        int pc = q * 256 + tid;
        brow[q] = pc >> 3;
        bchk[q] = (pc & 7) ^ (brow[q] & 7);
    }

    f32x4 acc[4][4];
#pragma unroll
    for (int m = 0; m < 4; ++m)
#pragma unroll
        for (int n = 0; n < 4; ++n) acc[m][n] = (f32x4)(0.0f);

    int fr = lane & 15;          // fragment row
    int h4 = lane >> 4;          // k-group within 32-k slice
    int s7 = fr & 7;             // swizzle key (wr*64, m*16 are 0 mod 8)

    const int nIter = K / BK;    // 16

    // ---------------- prologue ----------------
    float4 vA0[4], vA1[4];
    // load A(0) f32 -> regs
#pragma unroll
    for (int q = 0; q < 4; ++q) {
        const float* gp = A + (rowA0 + ar_[q]) * (long)K + acg_[q] * 8;
        vA0[q] = ((const float4*)gp)[0];
        vA1[q] = ((const float4*)gp)[1];
    }
    // glds B(0) -> Bs[0]
#pragma unroll
    for (int q = 0; q < 4; ++q) {
        const unsigned short* gp = Bt + (colB0 + brow[q]) * (long)K + bchk[q] * 8;
        async_copy16(gp, (unsigned short*)Bs[0] + q * 2048 + wave * 512);
    }
    // cvt A(0) -> As[0]   (compiler waits on the vA loads)
#pragma unroll
    for (int q = 0; q < 4; ++q) {
        uint4 w;
        w.x = cvt_pk_bf16(vA0[q].x, vA0[q].y);
        w.y = cvt_pk_bf16(vA0[q].z, vA0[q].w);
        w.z = cvt_pk_bf16(vA1[q].x, vA1[q].y);
        w.w = cvt_pk_bf16(vA1[q].z, vA1[q].w);
        *(uint4*)(&As[0][ar_[q] * 64 + acl_[q] * 8]) = w;
    }
    // load A(1) f32 -> regs
#pragma unroll
    for (int q = 0; q < 4; ++q) {
        const float* gp = A + (rowA0 + ar_[q]) * (long)K + BK + acg_[q] * 8;
        vA0[q] = ((const float4*)gp)[0];
        vA1[q] = ((const float4*)gp)[1];
    }
    __syncthreads();   // drains B(0) glds, A(1) reg loads, As[0] writes

    // ---------------- main loop (ONE barrier per iter) ----------------
    for (int it = 0; it < nIter; ++it) {
        int cur = it & 1;

        // prefetch B(it+1) -> Bs[cur^1] (readers finished before last barrier)
        if (it + 1 < nIter) {
            long k1 = (long)(it + 1) * BK;
#pragma unroll
            for (int q = 0; q < 4; ++q) {
                const unsigned short* gp =
                    Bt + (colB0 + brow[q]) * (long)K + k1 + bchk[q] * 8;
                async_copy16(gp, (unsigned short*)Bs[cur ^ 1] + q * 2048 + wave * 512);
            }
        }
        // cvt A(it+1) (regs arrived: barrier drained vmcnt) -> As[cur^1]
        if (it + 1 < nIter) {
#pragma unroll
            for (int q = 0; q < 4; ++q) {
                uint4 w;
                w.x = cvt_pk_bf16(vA0[q].x, vA0[q].y);
                w.y = cvt_pk_bf16(vA0[q].z, vA0[q].w);
                w.z = cvt_pk_bf16(vA1[q].x, vA1[q].y);
                w.w = cvt_pk_bf16(vA1[q].z, vA1[q].w);
                *(uint4*)(&As[cur ^ 1][ar_[q] * 64 + acl_[q] * 8]) = w;
            }
        }
        // issue A(it+2) f32 reg loads (after the cvt consumed the old values)
        if (it + 2 < nIter) {
            long k2 = (long)(it + 2) * BK;
#pragma unroll
            for (int q = 0; q < 4; ++q) {
                const float* gp = A + (rowA0 + ar_[q]) * (long)K + k2 + acg_[q] * 8;
                vA0[q] = ((const float4*)gp)[0];
                vA1[q] = ((const float4*)gp)[1];
            }
        }

        // compute on As[cur], Bs[cur]: two 16x16x32 k-slices
#pragma unroll
        for (int kk = 0; kk < 2; ++kk) {
            bf16x8 a[4], b[4];
            int cidx = kk * 4 + h4;           // logical chunk 0..7
            int cpos = cidx ^ s7;             // swizzled position
#pragma unroll
            for (int m = 0; m < 4; ++m) {
                int row = wr * 64 + m * 16 + fr;
                a[m] = *(const bf16x8*)(&As[cur][row * 64 + cpos * 8]);
            }
#pragma unroll
            for (int n = 0; n < 4; ++n) {
                int row = wc * 64 + n * 16 + fr;
                b[n] = *(const bf16x8*)(&Bs[cur][row * 64 + cpos * 8]);
            }
#pragma unroll
            for (int m = 0; m < 4; ++m)
#pragma unroll
                for (int n = 0; n < 4; ++n)
                    acc[m][n] = __builtin_amdgcn_mfma_f32_16x16x32_bf16(a[m], b[n], acc[m][n], 0, 0, 0);
        }

        __syncthreads();  // drains this iter's glds + reg loads + all ds ops
    }

    // epilogue: C[row][col] = acc + bias[col]
    int ccol = lane & 15;
    int crow = (lane >> 4) * 4;
#pragma unroll
    for (int m = 0; m < 4; ++m) {
        long grow = rowA0 + wr * 64 + m * 16 + crow;
#pragma unroll
        for (int n = 0; n < 4; ++n) {
            long gcol = colB0 + wc * 64 + n * 16 + ccol;
            float bb = bias[gcol];
#pragma unroll
            for (int r = 0; r < 4; ++r) {
                C[(grow + r) * N + gcol] = acc[m][n][r] + bb;
            }
        }
    }
}

// ---------------------------------------------------------------------------
// Fallback: plain f32 tiled GEMM (used only if ws too small for bf16 path)
__global__ __launch_bounds__(256)
void gemm_f32_fallback(const float* __restrict__ A, const float* __restrict__ Bt,
                       const float* __restrict__ bias, float* __restrict__ C,
                       int M, int N, int K) {
    __shared__ float As[64][17];
    __shared__ float Bs[64][17];
    int tilesN = N / 64;
    int tm = blockIdx.x / tilesN;
    int tn = blockIdx.x % tilesN;
    int tid = threadIdx.x;
    int tr = tid / 16, tc = tid % 16;
    float acc[4][4] = {};
    for (int k0 = 0; k0 < K; k0 += 16) {
        for (int t = tid; t < 64 * 16; t += 256) {
            int r = t / 16, c = t % 16;
            As[r][c] = A[((long)tm * 64 + r) * K + k0 + c];
            Bs[r][c] = Bt[((long)tn * 64 + r) * K + k0 + c];
        }
        __syncthreads();
#pragma unroll
        for (int kk = 0; kk < 16; ++kk) {
            float av[4], bv[4];
#pragma unroll
            for (int i = 0; i < 4; ++i) av[i] = As[tr * 4 + i][kk];
#pragma unroll
            for (int j = 0; j < 4; ++j) bv[j] = Bs[tc * 4 + j][kk];
#pragma unroll
            for (int i = 0; i < 4; ++i)
#pragma unroll
                for (int j = 0; j < 4; ++j) acc[i][j] += av[i] * bv[j];
        }
        __syncthreads();
    }
#pragma unroll
    for (int i = 0; i < 4; ++i) {
        long row = (long)tm * 64 + tr * 4 + i;
#pragma unroll
        for (int j = 0; j < 4; ++j) {
            long col = (long)tn * 64 + tc * 4 + j;
            C[row * N + col] = acc[i][j] + bias[col];
        }
    }
}

// ---------------------------------------------------------------------------
extern "C" void kernel_launch(void* const* d_in, const int* in_sizes, int n_in,
                              void* d_out, int out_size, void* d_ws, size_t ws_size,
                              hipStream_t stream) {
    const float* hs        = (const float*)d_in[0];
    const float* W         = (const float*)d_in[1];
    const float* b         = (const float*)d_in[2];
    const float* lora_down = (const float*)d_in[3];
    const float* lora_up   = (const float*)d_in[4];
    const float* down_aux  = (const float*)d_in[5];
    const float* up_aux    = (const float*)d_in[6];
    float* out = (float*)d_out;

    const int K = 1024;   // IN
    const int N = 1024;   // OUT
    const int M = in_sizes[0] / K;  // B*S = 65536

    char* ws = (char*)d_ws;
    // layout: t2 f32 [50*1024] @0 ; weff @256KB (bf16: 2MB, f32 fallback: 4MB)
    float* t2 = (float*)ws;
    const size_t OFF_WEFF = 256 * 1024;
    const size_t NEED_FAST = OFF_WEFF + 2 * 1024 * 1024;

    // Step 1a: t2
    lilora_t2_kernel<<<1, 1024, 0, stream>>>(lora_down, lora_up, down_aux, t2);

    if (ws_size >= NEED_FAST) {
        unsigned short* weff = (unsigned short*)(ws + OFF_WEFF);
        // Step 1b: W_eff bf16
        weff_bf16_kernel<<<N, 256, 0, stream>>>(W, up_aux, t2, weff);
        // Step 2: fused cvt+GEMM
        int grid = (M / BM) * (N / BN);
        gemm_fused_kernel<<<grid, 256, 0, stream>>>(hs, weff, b, out, M, N, K);
    } else {
        // fallback: f32 path (needs ~4.3 MB ws)
        float* weff = (float*)(ws + OFF_WEFF);
        weff_f32_kernel<<<N, 256, 0, stream>>>(W, up_aux, t2, weff);
        int grid = (M / 64) * (N / 64);
        gemm_f32_fallback<<<grid, 256, 0, stream>>>(hs, weff, b, out, M, N, K);
    }
}

// Round 5
// 273.691 us; speedup vs baseline: 1.0128x; 1.0128x over previous
//
#include <hip/hip_runtime.h>
#include <hip/hip_bf16.h>
#include <stdint.h>

#define ALPHA 1.0f

typedef __attribute__((ext_vector_type(8))) short bf16x8;
typedef __attribute__((ext_vector_type(4))) float f32x4;

__device__ __forceinline__ unsigned short f32_to_bf16_rne(float f) {
    union { float f; unsigned int u; } v; v.f = f;
    unsigned int u = v.u;
    unsigned int r = u + 0x7FFFu + ((u >> 16) & 1u);
    return (unsigned short)(r >> 16);
}

// packed f32x2 -> bf16x2 (RNE), single VALU instruction; word = [lo | hi<<16]
__device__ __forceinline__ unsigned int cvt_pk_bf16(float lo, float hi) {
    unsigned int r;
    asm("v_cvt_pk_bf16_f32 %0, %1, %2" : "=v"(r) : "v"(lo), "v"(hi));
    return r;
}

__device__ __forceinline__ void async_copy16(const void* g, void* l) {
    __builtin_amdgcn_global_load_lds(
        (const __attribute__((address_space(1))) void*)g,
        (__attribute__((address_space(3))) void*)l, 16, 0, 0);
}

// ---------------------------------------------------------------------------
// Step 1a: t2[50][1024] = lora_up (50x4) @ (lora_down (4x100) @ down_aux (100x1024))
__global__ void lilora_t2_kernel(const float* __restrict__ lora_down,
                                 const float* __restrict__ lora_up,
                                 const float* __restrict__ down_aux,
                                 float* __restrict__ t2) {
    int i = threadIdx.x;  // 0..1023 column
    float t1[4] = {0.f, 0.f, 0.f, 0.f};
    for (int d = 0; d < 100; ++d) {
        float da = down_aux[d * 1024 + i];
#pragma unroll
        for (int r = 0; r < 4; ++r) t1[r] += lora_down[r * 100 + d] * da;
    }
    for (int u = 0; u < 50; ++u) {
        float acc = 0.f;
#pragma unroll
        for (int r = 0; r < 4; ++r) acc += lora_up[u * 4 + r] * t1[r];
        t2[u * 1024 + i] = acc;
    }
}

// ---------------------------------------------------------------------------
// Step 1b: W_eff[o][i] = W[o][i] + ALPHA * sum_u up_aux[o][u] * t2[u][i]  (bf16 out)
__global__ __launch_bounds__(256)
void weff_bf16_kernel(const float* __restrict__ W, const float* __restrict__ up_aux,
                      const float* __restrict__ t2, unsigned short* __restrict__ weff) {
    int o = blockIdx.x;
    int i0 = threadIdx.x * 4;
    float4 acc = *(const float4*)(W + (long)o * 1024 + i0);
    for (int u = 0; u < 50; ++u) {
        float s = up_aux[o * 50 + u] * ALPHA;
        float4 t = *(const float4*)(t2 + u * 1024 + i0);
        acc.x += s * t.x; acc.y += s * t.y; acc.z += s * t.z; acc.w += s * t.w;
    }
    ushort4 r;
    r.x = f32_to_bf16_rne(acc.x);
    r.y = f32_to_bf16_rne(acc.y);
    r.z = f32_to_bf16_rne(acc.z);
    r.w = f32_to_bf16_rne(acc.w);
    *(ushort4*)(weff + (long)o * 1024 + i0) = r;
}

// f32 variant for the fallback path
__global__ __launch_bounds__(256)
void weff_f32_kernel(const float* __restrict__ W, const float* __restrict__ up_aux,
                     const float* __restrict__ t2, float* __restrict__ weff) {
    int o = blockIdx.x;
    int i0 = threadIdx.x * 4;
    float4 acc = *(const float4*)(W + (long)o * 1024 + i0);
    for (int u = 0; u < 50; ++u) {
        float s = up_aux[o * 50 + u] * ALPHA;
        float4 t = *(const float4*)(t2 + u * 1024 + i0);
        acc.x += s * t.x; acc.y += s * t.y; acc.z += s * t.z; acc.w += s * t.w;
    }
    *(float4*)(weff + (long)o * 1024 + i0) = acc;
}

// ---------------------------------------------------------------------------
// Fused GEMM: C[M][N] = cvt_bf16(A_f32[M][K]) * Bt_bf16[N][K]^T + bias
// 128x128 tile, BK=64, SINGLE-buffered LDS (32 KB), 2 barriers/iter (R1's
// proven occupancy profile), 4 waves (2x2), wave = 64x64 = 4x4 frags 16x16x32.
//
//  - B: global_load_lds bf16, PRE-SWIZZLED global source (rule #21).
//  - A: f32 global->reg (coalesced 32B/lane), cvt_pk once per element,
//    swizzled ds_write. vA loads for iter t+1 are issued in iter t's stage
//    phase, so the barrier-2 vmcnt drain gives them full arrival cover and
//    the cvt after the NEXT barrier never stalls.
//  - Both LDS tiles [row][64 bf16 = 8 x 16B chunks], chunk' = chunk ^ (row&7)
//    (R4-verified: 0 bank conflicts on this exact read/write pattern).
#define BM 128
#define BN 128
#define BK 64

__global__ __launch_bounds__(256, 3)
void gemm_fused_kernel(const float* __restrict__ A,
                       const unsigned short* __restrict__ Bt,
                       const float* __restrict__ bias,
                       float* __restrict__ C, int M, int N, int K) {
    __shared__ __align__(16) unsigned short As[BM * BK];  // 16 KB
    __shared__ __align__(16) unsigned short Bs[BN * BK];  // 16 KB

    int nTilesN = N / BN;
    int nwg = gridDim.x;
    int bid = blockIdx.x;
    // XCD-aware swizzle (bijective when nwg % 8 == 0; here grid = 4096)
    int swz = bid;
    if ((nwg & 7) == 0) {
        int cpx = nwg >> 3;
        swz = (bid & 7) * cpx + (bid >> 3);
    }
    int tm = swz / nTilesN;   // tn fastest -> 8 blocks sharing an A panel
    int tn = swz % nTilesN;   // run back-to-back on the same XCD (A L2-hot)

    int tid = threadIdx.x;
    int lane = tid & 63;
    int wave = tid >> 6;   // 0..3
    int wr = wave >> 1;    // 0..1
    int wc = wave & 1;     // 0..1

    const long rowA0 = (long)tm * BM;
    const long colB0 = (long)tn * BN;

    // ---- A staging map: chunk p = q*256 + tid (q=0..3) covers 8 f32 (32B) --
    //   row ar = p>>3 (0..127), global chunk acg = p&7 (f32 col = acg*8),
    //   LDS chunk pos acl = acg ^ (ar&7)  [8 bf16 = 16B after cvt]
    int ar_[4], acg_[4], acl_[4];
#pragma unroll
    for (int q = 0; q < 4; ++q) {
        int p = q * 256 + tid;
        ar_[q]  = p >> 3;
        acg_[q] = p & 7;
        acl_[q] = acg_[q] ^ (ar_[q] & 7);
    }

    // ---- B staging map (glds, pre-swizzled source) ----
    int brow[4], bchk[4];
#pragma unroll
    for (int q = 0; q < 4; ++q) {
        int pc = q * 256 + tid;
        brow[q] = pc >> 3;
        bchk[q] = (pc & 7) ^ (brow[q] & 7);
    }

    f32x4 acc[4][4];
#pragma unroll
    for (int m = 0; m < 4; ++m)
#pragma unroll
        for (int n = 0; n < 4; ++n) acc[m][n] = (f32x4)(0.0f);

    int fr = lane & 15;          // fragment row
    int h4 = lane >> 4;          // k-group within 32-k slice
    int s7 = fr & 7;             // swizzle key (wr*64, m*16 are 0 mod 8)

    const int nIter = K / BK;    // 16

    // prologue: load A(0) f32 -> regs
    float4 vA0[4], vA1[4];
#pragma unroll
    for (int q = 0; q < 4; ++q) {
        const float* gp = A + (rowA0 + ar_[q]) * (long)K + acg_[q] * 8;
        vA0[q] = ((const float4*)gp)[0];
        vA1[q] = ((const float4*)gp)[1];
    }

    for (int it = 0; it < nIter; ++it) {
        long k0 = (long)it * BK;
        __syncthreads();   // readers of previous tile done

        // stage B(it) early (async; latency overlaps the cvt VALU below)
#pragma unroll
        for (int q = 0; q < 4; ++q) {
            const unsigned short* gp =
                Bt + (colB0 + brow[q]) * (long)K + k0 + bchk[q] * 8;
            async_copy16(gp, (unsigned short*)Bs + q * 2048 + wave * 512);
        }

        // stage A(it): cvt regs (arrived: drained at previous barrier) -> LDS
#pragma unroll
        for (int q = 0; q < 4; ++q) {
            uint4 w;
            w.x = cvt_pk_bf16(vA0[q].x, vA0[q].y);
            w.y = cvt_pk_bf16(vA0[q].z, vA0[q].w);
            w.z = cvt_pk_bf16(vA1[q].x, vA1[q].y);
            w.w = cvt_pk_bf16(vA1[q].z, vA1[q].w);
            *(uint4*)(&As[ar_[q] * 64 + acl_[q] * 8]) = w;
        }

        // issue A(it+1) f32 loads now: they drain at the barrier below,
        // giving them the whole glds-drain window; cvt next iter won't stall
        if (it + 1 < nIter) {
            long k1 = k0 + BK;
#pragma unroll
            for (int q = 0; q < 4; ++q) {
                const float* gp = A + (rowA0 + ar_[q]) * (long)K + k1 + acg_[q] * 8;
                vA0[q] = ((const float4*)gp)[0];
                vA1[q] = ((const float4*)gp)[1];
            }
        }

        __syncthreads();   // drains glds B + A reg loads + ds_writes

        // MFMA: two 16x16x32 k-slices over BK=64
#pragma unroll
        for (int kk = 0; kk < 2; ++kk) {
            bf16x8 a[4], b[4];
            int cpos = (kk * 4 + h4) ^ s7;    // swizzled 16B-chunk position
#pragma unroll
            for (int m = 0; m < 4; ++m) {
                int row = wr * 64 + m * 16 + fr;
                a[m] = *(const bf16x8*)(&As[row * 64 + cpos * 8]);
            }
#pragma unroll
            for (int n = 0; n < 4; ++n) {
                int row = wc * 64 + n * 16 + fr;
                b[n] = *(const bf16x8*)(&Bs[row * 64 + cpos * 8]);
            }
#pragma unroll
            for (int m = 0; m < 4; ++m)
#pragma unroll
                for (int n = 0; n < 4; ++n)
                    acc[m][n] = __builtin_amdgcn_mfma_f32_16x16x32_bf16(a[m], b[n], acc[m][n], 0, 0, 0);
        }
    }

    // epilogue: C[row][col] = acc + bias[col]
    int ccol = lane & 15;
    int crow = (lane >> 4) * 4;
#pragma unroll
    for (int m = 0; m < 4; ++m) {
        long grow = rowA0 + wr * 64 + m * 16 + crow;
#pragma unroll
        for (int n = 0; n < 4; ++n) {
            long gcol = colB0 + wc * 64 + n * 16 + ccol;
            float bb = bias[gcol];
#pragma unroll
            for (int r = 0; r < 4; ++r) {
                C[(grow + r) * N + gcol] = acc[m][n][r] + bb;
            }
        }
    }
}

// ---------------------------------------------------------------------------
// Fallback: plain f32 tiled GEMM (used only if ws too small for bf16 path)
__global__ __launch_bounds__(256)
void gemm_f32_fallback(const float* __restrict__ A, const float* __restrict__ Bt,
                       const float* __restrict__ bias, float* __restrict__ C,
                       int M, int N, int K) {
    __shared__ float As[64][17];
    __shared__ float Bs[64][17];
    int tilesN = N / 64;
    int tm = blockIdx.x / tilesN;
    int tn = blockIdx.x % tilesN;
    int tid = threadIdx.x;
    int tr = tid / 16, tc = tid % 16;
    float acc[4][4] = {};
    for (int k0 = 0; k0 < K; k0 += 16) {
        for (int t = tid; t < 64 * 16; t += 256) {
            int r = t / 16, c = t % 16;
            As[r][c] = A[((long)tm * 64 + r) * K + k0 + c];
            Bs[r][c] = Bt[((long)tn * 64 + r) * K + k0 + c];
        }
        __syncthreads();
#pragma unroll
        for (int kk = 0; kk < 16; ++kk) {
            float av[4], bv[4];
#pragma unroll
            for (int i = 0; i < 4; ++i) av[i] = As[tr * 4 + i][kk];
#pragma unroll
            for (int j = 0; j < 4; ++j) bv[j] = Bs[tc * 4 + j][kk];
#pragma unroll
            for (int i = 0; i < 4; ++i)
#pragma unroll
                for (int j = 0; j < 4; ++j) acc[i][j] += av[i] * bv[j];
        }
        __syncthreads();
    }
#pragma unroll
    for (int i = 0; i < 4; ++i) {
        long row = (long)tm * 64 + tr * 4 + i;
#pragma unroll
        for (int j = 0; j < 4; ++j) {
            long col = (long)tn * 64 + tc * 4 + j;
            C[row * N + col] = acc[i][j] + bias[col];
        }
    }
}

// ---------------------------------------------------------------------------
extern "C" void kernel_launch(void* const* d_in, const int* in_sizes, int n_in,
                              void* d_out, int out_size, void* d_ws, size_t ws_size,
                              hipStream_t stream) {
    const float* hs        = (const float*)d_in[0];
    const float* W         = (const float*)d_in[1];
    const float* b         = (const float*)d_in[2];
    const float* lora_down = (const float*)d_in[3];
    const float* lora_up   = (const float*)d_in[4];
    const float* down_aux  = (const float*)d_in[5];
    const float* up_aux    = (const float*)d_in[6];
    float* out = (float*)d_out;

    const int K = 1024;   // IN
    const int N = 1024;   // OUT
    const int M = in_sizes[0] / K;  // B*S = 65536

    char* ws = (char*)d_ws;
    // layout: t2 f32 [50*1024] @0 ; weff @256KB (bf16: 2MB, f32 fallback: 4MB)
    float* t2 = (float*)ws;
    const size_t OFF_WEFF = 256 * 1024;
    const size_t NEED_FAST = OFF_WEFF + 2 * 1024 * 1024;

    // Step 1a: t2
    lilora_t2_kernel<<<1, 1024, 0, stream>>>(lora_down, lora_up, down_aux, t2);

    if (ws_size >= NEED_FAST) {
        unsigned short* weff = (unsigned short*)(ws + OFF_WEFF);
        // Step 1b: W_eff bf16
        weff_bf16_kernel<<<N, 256, 0, stream>>>(W, up_aux, t2, weff);
        // Step 2: fused cvt+GEMM
        int grid = (M / BM) * (N / BN);
        gemm_fused_kernel<<<grid, 256, 0, stream>>>(hs, weff, b, out, M, N, K);
    } else {
        // fallback: f32 path (needs ~4.3 MB ws)
        float* weff = (float*)(ws + OFF_WEFF);
        weff_f32_kernel<<<N, 256, 0, stream>>>(W, up_aux, t2, weff);
        int grid = (M / 64) * (N / 64);
        gemm_f32_fallback<<<grid, 256, 0, stream>>>(hs, weff, b, out, M, N, K);
    }
}